// Round 1
// 59.455 us; speedup vs baseline: 1.0543x; 1.0543x over previous
//
#include <hip/hip_runtime.h>
#include <math.h>

// noises [L=12, N=4096, D=16] fp32. Loss factorizes:
//   ce.sum()  = sum_l sum_d (sum_i p[l,i,d]) * (sum_j log_q[l,j,d])
//   diag_sum  = sum_{l,i,d} p*log_q   (per-row dot)
//   aux2 needs only sum_i p[l,i,d]
// Budget analysis: harness poisons the full 256 MiB workspace every
// iteration (~40.6 us fill dispatch, stream-ordered before us). Our
// controllable share is ~22 us. This version attacks it:
//   pass1: 768 blocks x 64 threads (1 wave, no LDS, no syncthreads),
//          halving-butterfly array reduction: 17 shuffles per 16-array
//          (vs 6 per scalar -> 198 total before, ~40 now).
//   partials stored value-major part[33][768] so pass2 reads are
//          contiguous float4s.
#define LAYERS 12
#define NROWS  4096
#define DDIM   16
#define BLOCK  64
#define NBLK   ((LAYERS * NROWS) / BLOCK)   // 768 blocks, 1 wave each
#define BLK_PER_LAYER (NROWS / BLOCK)       // 64 blocks per layer
#define PART   33                           // 16 sumP + 16 sumLQ + 1 diag
#define PBLK2  256

__device__ __forceinline__ float wave_red6(float v) {
    #pragma unroll
    for (int off = 32; off > 0; off >>= 1)
        v += __shfl_xor(v, off, 64);
    return v;
}

// Halving butterfly: v[16] per lane, 64 lanes. Returns, in EVERY lane,
// the full 64-lane sum of v[d] for d = (lane>>2)&15.
// Each shuffle exchanges complementary halves (one value serves both
// partners): 8+4+2+1 shuffles to 1 value/lane, +2 to fold the 4-lane
// redundancy. 17 shuffles total vs 96 for per-scalar trees.
__device__ __forceinline__ float red16(const float* v, int lane) {
    const bool b5 = lane & 32, b4 = lane & 16, b3 = lane & 8, b2 = lane & 4;
    float w8[8], w4[4], w2[2], w1;
    #pragma unroll
    for (int k = 0; k < 8; k++) {
        float t = b5 ? v[k] : v[k + 8];          // send what partner keeps
        float o = __shfl_xor(t, 32, 64);
        w8[k] = (b5 ? v[k + 8] : v[k]) + o;      // keep own half + partner's
    }
    #pragma unroll
    for (int k = 0; k < 4; k++) {
        float t = b4 ? w8[k] : w8[k + 4];
        float o = __shfl_xor(t, 16, 64);
        w4[k] = (b4 ? w8[k + 4] : w8[k]) + o;
    }
    #pragma unroll
    for (int k = 0; k < 2; k++) {
        float t = b3 ? w4[k] : w4[k + 2];
        float o = __shfl_xor(t, 8, 64);
        w2[k] = (b3 ? w4[k + 2] : w4[k]) + o;
    }
    {
        float t = b2 ? w2[0] : w2[1];
        float o = __shfl_xor(t, 4, 64);
        w1 = (b2 ? w2[1] : w2[0]) + o;
    }
    w1 += __shfl_xor(w1, 2, 64);
    w1 += __shfl_xor(w1, 1, 64);
    return w1;   // d = lane>>2  (bit5->8, bit4->4, bit3->2, bit2->1)
}

__global__ __launch_bounds__(BLOCK)
void moe_loss_pass1(const float* __restrict__ x, float* __restrict__ part) {
    const int lane = threadIdx.x;               // 64 threads = 1 wave
    const int b    = blockIdx.x;                // 64 consecutive rows/block

    const float4* x4 = (const float4*)x;
    const int r4 = (b * BLOCK + lane) * 4;      // row = b*64+lane, 16 floats
    float v[DDIM]; float4 a4;
    a4 = x4[r4 + 0]; v[0]  = a4.x; v[1]  = a4.y; v[2]  = a4.z; v[3]  = a4.w;
    a4 = x4[r4 + 1]; v[4]  = a4.x; v[5]  = a4.y; v[6]  = a4.z; v[7]  = a4.w;
    a4 = x4[r4 + 2]; v[8]  = a4.x; v[9]  = a4.y; v[10] = a4.z; v[11] = a4.w;
    a4 = x4[r4 + 3]; v[12] = a4.x; v[13] = a4.y; v[14] = a4.z; v[15] = a4.w;

    float m = v[0];
    #pragma unroll
    for (int d = 1; d < DDIM; d++) m = fmaxf(m, v[d]);
    float e[DDIM], s = 0.f;
    #pragma unroll
    for (int d = 0; d < DDIM; d++) { e[d] = __expf(v[d] - m); s += e[d]; }
    const float inv = __frcp_rn(s);

    float p[DDIM], lq[DDIM], diag = 0.f;
    #pragma unroll
    for (int d = 0; d < DDIM; d++) {
        p[d]  = e[d] * inv;
        lq[d] = __logf(p[d] + 1e-9f);
        diag += p[d] * lq[d];
    }

    const float sp = red16(p,  lane);   // full-wave sum of p[lane>>2]
    const float sl = red16(lq, lane);   // full-wave sum of lq[lane>>2]
    const float dg = wave_red6(diag);   // full-wave diag sum, all lanes

    // value-major partials: part[v*768 + b], v in [0,33)
    const int g = lane >> 2, sub = lane & 3;
    if (sub == 0) part[g * NBLK + b] = sp;
    if (sub == 1) part[(DDIM + g) * NBLK + b] = sl;
    if (lane == 2) part[32 * NBLK + b] = dg;
}

__global__ __launch_bounds__(PBLK2)
void moe_loss_pass2(const float* __restrict__ part, float* __restrict__ out) {
    const int tid  = threadIdx.x;
    const int wave = tid >> 6;
    const int lane = tid & 63;

    // thread tid = (l, d) for tid < 192; per-(l,d) partials are the 64
    // consecutive floats part[v*768 + l*64 .. +64) -> 16 float4 loads.
    __shared__ float sP[LAYERS][DDIM];
    const int l = tid >> 4, d = tid & 15;
    float a = 0.f, bq = 0.f;
    if (tid < LAYERS * DDIM) {
        const float4* pa = (const float4*)(part + d * NBLK + l * BLK_PER_LAYER);
        const float4* pb = (const float4*)(part + (DDIM + d) * NBLK + l * BLK_PER_LAYER);
        #pragma unroll
        for (int k = 0; k < BLK_PER_LAYER / 4; k++) {
            float4 va = pa[k]; a  += va.x + va.y + va.z + va.w;
            float4 vb = pb[k]; bq += vb.x + vb.y + vb.z + vb.w;
        }
        sP[l][d] = a;
    }
    __syncthreads();
    float ce_v = 0.f, lg_v = 0.f;
    if (tid < LAYERS * DDIM) {
        float S = 0.f;
        #pragma unroll
        for (int d2 = 0; d2 < DDIM; d2++) S += sP[l][d2];
        ce_v = a * bq;                        // -> ce.sum()
        lg_v = __logf(a / S + 1e-8f);         // -> aux2 (pm = a/S)
    }
    // diag partials: 768 values, 256 threads, 3 coalesced reads each
    const float* dgp = part + 32 * NBLK;
    const float dg_v = dgp[tid] + dgp[tid + 256] + dgp[tid + 512];

    __shared__ float red[3][PBLK2 / 64];
    const float r0 = wave_red6(ce_v), r1 = wave_red6(lg_v), r2 = wave_red6(dg_v);
    if (lane == 0) { red[0][wave] = r0; red[1][wave] = r1; red[2][wave] = r2; }
    __syncthreads();
    if (tid == 0) {
        const float ce = red[0][0] + red[0][1] + red[0][2] + red[0][3];
        const float lg = red[1][0] + red[1][1] + red[1][2] + red[1][3];
        const float dg = red[2][0] + red[2][1] + red[2][2] + red[2][3];
        const float aux1 = (ce - dg) / (2.0f * LAYERS);
        const float aux2 = (-lg / (float)DDIM) / (float)LAYERS;
        out[0] = 0.01f * (1.0f * aux1 + aux2);
    }
}

extern "C" void kernel_launch(void* const* d_in, const int* in_sizes, int n_in,
                              void* d_out, int out_size, void* d_ws, size_t ws_size,
                              hipStream_t stream) {
    const float* noises = (const float*)d_in[0];
    float* part = (float*)d_ws;                 // 33*768*4 = 101,376 B scratch
    float* out  = (float*)d_out;
    hipLaunchKernelGGL(moe_loss_pass1, dim3(NBLK), dim3(BLOCK), 0, stream, noises, part);
    hipLaunchKernelGGL(moe_loss_pass2, dim3(1), dim3(PBLK2), 0, stream, part, out);
}